// Round 1
// 973.052 us; speedup vs baseline: 1.1545x; 1.1545x over previous
//
#include <hip/hip_runtime.h>
#include <hip/hip_bf16.h>

// LinearLayer_PSLoRA: out = X @ W^T + bias + 0.5 * (X @ A[lab]) @ B_lora^T
// B=8, S=2048, D_IN=4096, D_OUT=4096, R=32, 5 labelers. All inputs fp32.
// bf16 MFMA; LoRA folded as one peeled K-step.
// R3: main_gemm ported to the 256x256 / BK=64 / 8-wave / 8-phase template:
//     k-half double-buffered LDS (128 KiB), counted vmcnt(4) at phases 4/8
//     (never 0 in the loop), raw s_barrier (no __syncthreads drain),
//     XOR col-swizzle (pre-swizzled global source + swizzled ds_read),
//     s_setprio(1) around MFMA clusters, XCD-aware block swizzle.

typedef __bf16 bf16_t;
typedef bf16_t bf16x4 __attribute__((ext_vector_type(4)));
typedef bf16_t bf16x8 __attribute__((ext_vector_type(8)));
typedef float f32x4 __attribute__((ext_vector_type(4)));

#define S_    2048
#define DIN   4096
#define DOUT  4096
#define R_    32
#define M_TOT 16384
#define KSPLIT 8

__device__ __forceinline__ void async_cp16(const bf16_t* g, bf16_t* l) {
  // global -> LDS direct DMA, 16B/lane; HW scatters lane i to base + i*16.
  __builtin_amdgcn_global_load_lds((const __attribute__((address_space(1))) void*)g,
                                   (__attribute__((address_space(3))) void*)l,
                                   16, 0, 0);
}

// ---------------------------------------------------------------- casts -----
__global__ void cast_f32_to_bf16(const float* __restrict__ src,
                                 bf16_t* __restrict__ dst, int n4) {
  int i = blockIdx.x * blockDim.x + threadIdx.x;
  if (i >= n4) return;
  f32x4 v = ((const f32x4*)src)[i];
  bf16x4 o = { (bf16_t)v[0], (bf16_t)v[1], (bf16_t)v[2], (bf16_t)v[3] };
  ((bf16x4*)dst)[i] = o;
}

// lora_A [5][DIN][R] fp32 -> At [5][R][DIN] bf16, coalesced via LDS tile.
__global__ __launch_bounds__(256) void transpose_loraA(
    const float* __restrict__ A, bf16_t* __restrict__ At) {
  __shared__ float tile[64][33];
  const int l = blockIdx.x / (DIN / 64);
  const int k0 = (blockIdx.x % (DIN / 64)) * 64;
  const int tid = threadIdx.x;
  {
    const int r = tid & 31, kb = tid >> 5;
#pragma unroll
    for (int p = 0; p < 8; ++p) {
      int k = p * 8 + kb;
      tile[k][r] = A[(size_t)l * DIN * R_ + (size_t)(k0 + k) * R_ + r];
    }
  }
  __syncthreads();
  {
    const int k = tid & 63, rb = tid >> 6;
#pragma unroll
    for (int p = 0; p < 8; ++p) {
      int r = p * 4 + rb;
      At[(size_t)l * R_ * DIN + (size_t)r * DIN + k0 + k] = (bf16_t)tile[k][r];
    }
  }
}

// ------------------------- axp[ks] = Xb[:, ks*512:+512] @ A[lab][ks-chunk] --
__global__ __launch_bounds__(256) void ax_partial(
    const bf16_t* __restrict__ Xb, const bf16_t* __restrict__ At,
    const int* __restrict__ lab_idx, float* __restrict__ axp) {
  __shared__ bf16_t As[128 * 64];
  __shared__ bf16_t Bs[32 * 64];
  const int tid = threadIdx.x, lane = tid & 63, wv = tid >> 6;
  const int m0 = blockIdx.x * 128;
  const int kbase = blockIdx.y * (DIN / KSPLIT);
  const int lab = lab_idx[m0 / S_];
  const bf16_t* Bsrc = At + (size_t)lab * R_ * DIN;

  f32x4 acc[2][2];
#pragma unroll
  for (int i = 0; i < 2; ++i)
#pragma unroll
    for (int j = 0; j < 2; ++j) acc[i][j] = (f32x4){0.f, 0.f, 0.f, 0.f};

  for (int kt = 0; kt < (DIN / KSPLIT) / 64; ++kt) {
    const int k0 = kbase + kt * 64;
    __syncthreads();
    {
      const int kk = (lane & 7) * 8;
#pragma unroll
      for (int j = 0; j < 4; ++j) {
        int row = j * 32 + wv * 8 + (lane >> 3);
        async_cp16(Xb + (size_t)(m0 + row) * DIN + k0 + kk,
                   As + j * 2048 + wv * 512);
      }
      int row = wv * 8 + (lane >> 3);
      async_cp16(Bsrc + (size_t)row * DIN + k0 + kk, Bs + wv * 512);
    }
    __syncthreads();
#pragma unroll
    for (int ks = 0; ks < 2; ++ks) {
      bf16x8 a[2], b[2];
#pragma unroll
      for (int mt = 0; mt < 2; ++mt)
        a[mt] = *(const bf16x8*)&As[(wv * 32 + mt * 16 + (lane & 15)) * 64 +
                                    ks * 32 + (lane >> 4) * 8];
#pragma unroll
      for (int nt = 0; nt < 2; ++nt)
        b[nt] = *(const bf16x8*)&Bs[(nt * 16 + (lane & 15)) * 64 +
                                    ks * 32 + (lane >> 4) * 8];
#pragma unroll
      for (int mt = 0; mt < 2; ++mt)
#pragma unroll
        for (int nt = 0; nt < 2; ++nt)
          acc[mt][nt] = __builtin_amdgcn_mfma_f32_16x16x32_bf16(
              a[mt], b[nt], acc[mt][nt], 0, 0, 0);
    }
  }
  float* dst = axp + (size_t)blockIdx.y * M_TOT * R_;
#pragma unroll
  for (int mt = 0; mt < 2; ++mt)
#pragma unroll
    for (int nt = 0; nt < 2; ++nt)
#pragma unroll
      for (int r = 0; r < 4; ++r) {
        int m = m0 + wv * 32 + mt * 16 + (lane >> 4) * 4 + r;
        int n = nt * 16 + (lane & 15);
        dst[(size_t)m * R_ + n] = acc[mt][nt][r];
      }
}

// axb = bf16( 0.5 * sum_ks axp[ks] )
__global__ void ax_reduce(const float* __restrict__ axp,
                          bf16_t* __restrict__ axb, int n4) {
  int i = blockIdx.x * blockDim.x + threadIdx.x;
  if (i >= n4) return;
  f32x4 s = (f32x4){0.f, 0.f, 0.f, 0.f};
#pragma unroll
  for (int ks = 0; ks < KSPLIT; ++ks)
    s += ((const f32x4*)(axp + (size_t)ks * M_TOT * R_))[i];
  bf16x4 o = { (bf16_t)(0.5f * s[0]), (bf16_t)(0.5f * s[1]),
               (bf16_t)(0.5f * s[2]), (bf16_t)(0.5f * s[3]) };
  ((bf16x4*)axb)[i] = o;
}

// ------------------------------------- out = [Xb|axb] @ [Wb|Bb]^T + bias ----
// 256x256 tile, BK=64, 512 threads = 8 waves (2M x 4N), each wave 128x64.
// LDS [buf][op][khalf][256 rows * 32 cols] = 128 KiB, k-half double buffer.
// 8 phases / iteration, 2 K-tiles / iteration; vmcnt(4) only at phases 4/8.
// Col-swizzle: 16B slot index ^= (row>>1)&3 (pre-swizzled global source on
// the staging side, swizzled address on the ds_read side).
__global__ __launch_bounds__(512, 2) void main_gemm(
    const bf16_t* __restrict__ Xb, const bf16_t* __restrict__ Wb,
    const bf16_t* __restrict__ axb, const bf16_t* __restrict__ Bb,
    const float* __restrict__ bias, float* __restrict__ out) {
  __shared__ bf16_t lds[2][2][2][8192];  // [buf][A/B][kh][256*32] = 128 KiB
  char* ldsb = (char*)&lds[0][0][0][0];

  const int tid = threadIdx.x, lane = tid & 63, wv = tid >> 6;
  const int wm = wv & 1, wn = wv >> 1;

  // XCD-aware swizzle: 1024 blocks, 8 XCDs, 128 contiguous per XCD.
  const int swz = (blockIdx.x & 7) * 128 + (blockIdx.x >> 3);
  const int m0 = (swz >> 4) * 256, n0 = (swz & 15) * 256;

  // ---- read side: frag (row = base+(lane&15), k = ks*32+(lane>>4)*8) ------
  // byte within region = row*64 + ((hi ^ ((row>>1)&3)) << 4)
  const int rd_off = (lane & 15) * 64 + ((((lane >> 4) ^ (lane >> 1)) & 3) << 4);
  const char* ldsA0 = ldsb + wm * 8192 + rd_off;           // buf0 A
  const char* ldsA1 = ldsA0 + 65536;                       // buf1 A
  const char* ldsB0 = ldsb + 32768 + wn * 4096 + rd_off;   // buf0 B
  const char* ldsB1 = ldsB0 + 65536;                       // buf1 B

  // ---- stage side: wave wv writes 1KB at region + (j*8+wv)*1024 -----------
  // phys (row = (j*8+wv)*16 + lane>>2, slot = lane&3) holds logical
  // column (lane&3) ^ ((lane>>3)&3) -> pre-swizzle the global source.
  const int srow = lane >> 2;
  const int scol = (((lane & 3) ^ (lane >> 3)) & 3) * 8;
  const bf16_t* pA_w = Xb + (size_t)(m0 + wv * 16 + srow) * DIN + scol;
  const bf16_t* pB_w = Wb + (size_t)(n0 + wv * 16 + srow) * DIN + scol;
  char* lAw = ldsb + wv * 1024;
  char* lBw = ldsb + 32768 + wv * 1024;

  f32x4 acc[8][4];
#pragma unroll
  for (int i = 0; i < 8; ++i)
#pragma unroll
    for (int j = 0; j < 4; ++j) acc[i][j] = (f32x4){0.f, 0.f, 0.f, 0.f};

#define STAGE_A(buf, kh, st) do {                                        \
    const bf16_t* g_ = pA_w + (st) * 64 + (kh) * 32;                     \
    bf16_t* l_ = (bf16_t*)(lAw + (buf) * 65536 + (kh) * 16384);          \
    async_cp16(g_, l_);                                                  \
    async_cp16(g_ + 128 * DIN, l_ + 4096);                               \
  } while (0)

#define STAGE_B(buf, kh, st) do {                                        \
    const bf16_t* g_ = pB_w + (st) * 64 + (kh) * 32;                     \
    bf16_t* l_ = (bf16_t*)(lBw + (buf) * 65536 + (kh) * 16384);          \
    async_cp16(g_, l_);                                                  \
    async_cp16(g_ + 128 * DIN, l_ + 4096);                               \
  } while (0)

  bf16x8 bfr[4];

  // One phase: ds-load subtile || stage one half-tile -> barrier ->
  // lgkmcnt(0) -> setprio(1) 16xMFMA setprio(0) -> [vmcnt] -> barrier.
#define PHASE(buf, ks, mh, LOADB, STAGE_STMT, VM) do {                   \
    const char* pa_ = (buf) ? ldsA1 : ldsA0;                             \
    const char* pb_ = (buf) ? ldsB1 : ldsB0;                             \
    bf16x8 a_[4];                                                        \
    _Pragma("unroll")                                                    \
    for (int m_ = 0; m_ < 4; ++m_)                                       \
      a_[m_] = *(const bf16x8*)(pa_ + (ks) * 16384 + ((mh) * 4 + m_) * 1024); \
    if (LOADB) {                                                         \
      _Pragma("unroll")                                                  \
      for (int n_ = 0; n_ < 4; ++n_)                                     \
        bfr[n_] = *(const bf16x8*)(pb_ + (ks) * 16384 + n_ * 1024);      \
    }                                                                    \
    STAGE_STMT;                                                          \
    __builtin_amdgcn_s_barrier();                                        \
    asm volatile("s_waitcnt lgkmcnt(0)" ::: "memory");                   \
    __builtin_amdgcn_s_setprio(1);                                       \
    _Pragma("unroll")                                                    \
    for (int m_ = 0; m_ < 4; ++m_)                                       \
      _Pragma("unroll")                                                  \
      for (int n_ = 0; n_ < 4; ++n_)                                     \
        acc[(mh) * 4 + m_][n_] = __builtin_amdgcn_mfma_f32_16x16x32_bf16( \
            a_[m_], bfr[n_], acc[(mh) * 4 + m_][n_], 0, 0, 0);           \
    __builtin_amdgcn_s_setprio(0);                                       \
    VM;                                                                  \
    __builtin_amdgcn_s_barrier();                                        \
  } while (0)

  // ---- prologue: buf0 (tile 0, both k-halves) + buf1.k0 (tile 1) ----------
  STAGE_A(0, 0, 0); STAGE_B(0, 0, 0);
  STAGE_A(0, 1, 0); STAGE_B(0, 1, 0);
  STAGE_A(1, 0, 1); STAGE_B(1, 0, 1);
  asm volatile("s_waitcnt vmcnt(4)" ::: "memory");  // buf0 fully landed
  __builtin_amdgcn_s_barrier();

  // ---- main loop: iteration i computes tiles 2i (buf0) and 2i+1 (buf1) ----
  // Stage map: P1 A(2i+1).k1->buf1  P2 B(2i+1).k1->buf1
  //            P3 A(2i+2).k0->buf0  P4 B(2i+2).k0->buf0  [vmcnt(4)]
  //            P5 A(2i+2).k1->buf0  P6 B(2i+2).k1->buf0
  //            P7 A(2i+3).k0->buf1  P8 B(2i+3).k0->buf1  [vmcnt(4)]
  for (int i = 0; i < 32; ++i) {
    const int st1 = 2 * i + 1;
    const int st2 = (2 * i + 2 < 64) ? 2 * i + 2 : 63;  // clamp: tail restage
    const int st3 = (2 * i + 3 < 64) ? 2 * i + 3 : 63;  // lands in dead regions
    PHASE(0, 0, 0, 1, STAGE_A(1, 1, st1), );
    PHASE(0, 0, 1, 0, STAGE_B(1, 1, st1), );
    PHASE(0, 1, 0, 1, STAGE_A(0, 0, st2), );
    PHASE(0, 1, 1, 0, STAGE_B(0, 0, st2),
          asm volatile("s_waitcnt vmcnt(4)" ::: "memory"));
    PHASE(1, 0, 0, 1, STAGE_A(0, 1, st2), );
    PHASE(1, 0, 1, 0, STAGE_B(0, 1, st2), );
    PHASE(1, 1, 0, 1, STAGE_A(1, 0, st3), );
    PHASE(1, 1, 1, 0, STAGE_B(1, 0, st3),
          asm volatile("s_waitcnt vmcnt(4)" ::: "memory"));
  }

  // ---- peeled LoRA K-step (K=32) into buf0.k0 -----------------------------
  // buf0.k0's prior (clamped) stages completed at PH8's vmcnt(4); only
  // PH7/PH8 loads (buf1.k0) remain in flight -> disjoint, safe to restage.
  {
    const bf16_t* gA = axb + (size_t)(m0 + wv * 16 + srow) * R_ + scol;
    const bf16_t* gB = Bb + (size_t)(n0 + wv * 16 + srow) * R_ + scol;
    bf16_t* lA = (bf16_t*)lAw;
    bf16_t* lB = (bf16_t*)lBw;
    async_cp16(gA, lA); async_cp16(gA + 128 * R_, lA + 4096);
    async_cp16(gB, lB); async_cp16(gB + 128 * R_, lB + 4096);
    asm volatile("s_waitcnt vmcnt(0)" ::: "memory");
    __builtin_amdgcn_s_barrier();
    bf16x8 a8[8];
#pragma unroll
    for (int m = 0; m < 8; ++m)
      a8[m] = *(const bf16x8*)(ldsA0 + m * 1024);
#pragma unroll
    for (int n = 0; n < 4; ++n)
      bfr[n] = *(const bf16x8*)(ldsB0 + n * 1024);
    asm volatile("s_waitcnt lgkmcnt(0)" ::: "memory");
#pragma unroll
    for (int m = 0; m < 8; ++m)
#pragma unroll
      for (int n = 0; n < 4; ++n)
        acc[m][n] = __builtin_amdgcn_mfma_f32_16x16x32_bf16(
            a8[m], bfr[n], acc[m][n], 0, 0, 0);
  }
#undef PHASE
#undef STAGE_A
#undef STAGE_B

  // ---- epilogue: +bias, fp32 store. C/D: col=lane&15, row=(lane>>4)*4+reg -
#pragma unroll
  for (int nf = 0; nf < 4; ++nf) {
    const int n = n0 + wn * 64 + nf * 16 + (lane & 15);
    const float bv = bias[n];
#pragma unroll
    for (int mf = 0; mf < 8; ++mf) {
      const int m = m0 + wm * 128 + mf * 16 + (lane >> 4) * 4;
#pragma unroll
      for (int r = 0; r < 4; ++r)
        out[(size_t)(m + r) * DOUT + n] = acc[mf][nf][r] + bv;
    }
  }
}

// ---------------------------------------------------------------------------
extern "C" void kernel_launch(void* const* d_in, const int* in_sizes, int n_in,
                              void* d_out, int out_size, void* d_ws, size_t ws_size,
                              hipStream_t stream) {
  const float* X      = (const float*)d_in[0];  // [8,2048,4096]
  const float* W      = (const float*)d_in[1];  // [4096,4096]
  const float* bias   = (const float*)d_in[2];  // [4096]
  const float* lora_A = (const float*)d_in[3];  // [5,4096,32]
  const float* lora_B = (const float*)d_in[4];  // [4096,32]
  const int*   lab    = (const int*)d_in[5];    // [8]
  float* out = (float*)d_out;

  // ws layout (bytes): Xb 128M | Wb 32M | At 1.25M | Bb 256K | axb 1M | axp 16M
  char* ws = (char*)d_ws;
  bf16_t* Xb  = (bf16_t*)(ws);
  bf16_t* Wb  = (bf16_t*)(ws + 134217728UL);
  bf16_t* At  = (bf16_t*)(ws + 167772160UL);
  bf16_t* Bb  = (bf16_t*)(ws + 169082880UL);
  bf16_t* axb = (bf16_t*)(ws + 169345024UL);
  float*  axp = (float*)(ws + 170393600UL);   // 16 MB, ends at ~187 MB

  cast_f32_to_bf16<<<65536, 256, 0, stream>>>(X, Xb, (M_TOT * DIN) / 4);
  cast_f32_to_bf16<<<16384, 256, 0, stream>>>(W, Wb, (DOUT * DIN) / 4);
  cast_f32_to_bf16<<<128, 256, 0, stream>>>(lora_B, Bb, (DOUT * R_) / 4);
  transpose_loraA<<<5 * (DIN / 64), 256, 0, stream>>>(lora_A, At);
  ax_partial<<<dim3(M_TOT / 128, KSPLIT), 256, 0, stream>>>(Xb, At, lab, axp);
  ax_reduce<<<(M_TOT * R_ / 4 + 255) / 256, 256, 0, stream>>>(
      axp, axb, M_TOT * R_ / 4);
  main_gemm<<<1024, 512, 0, stream>>>(Xb, Wb, axb, Bb, bias, out);
}

// Round 3
// 968.192 us; speedup vs baseline: 1.1603x; 1.0050x over previous
//
#include <hip/hip_runtime.h>
#include <hip/hip_bf16.h>

// LinearLayer_PSLoRA: out = X @ W^T + bias + 0.5 * (X @ A[lab]) @ B_lora^T
// B=8, S=2048, D_IN=4096, D_OUT=4096, R=32, 5 labelers. All inputs fp32.
// R5 (= R4 resubmit + defensive vmcnt(0) drain before epilogue; prior round
//     died to a container infra error, not a kernel failure).
// Folded LoRA: Wl[l] = W + 0.5 * B_lora @ A[l]^T (rank-32 update, one K=32
// MFMA per 16x16 frag). main_gemm_wl reads Wl[lab] directly; the whole
// ax side-path disappears. Needs 288 MB ws; falls back to the verified R3
// pipeline if ws_size is too small.

typedef __bf16 bf16_t;
typedef bf16_t bf16x4 __attribute__((ext_vector_type(4)));
typedef bf16_t bf16x8 __attribute__((ext_vector_type(8)));
typedef float f32x4 __attribute__((ext_vector_type(4)));

#define S_    2048
#define DIN   4096
#define DOUT  4096
#define R_    32
#define M_TOT 16384
#define KSPLIT 8

__device__ __forceinline__ void async_cp16(const bf16_t* g, bf16_t* l) {
  // global -> LDS direct DMA, 16B/lane; HW scatters lane i to base + i*16.
  __builtin_amdgcn_global_load_lds((const __attribute__((address_space(1))) void*)g,
                                   (__attribute__((address_space(3))) void*)l,
                                   16, 0, 0);
}

// ---------------------------------------------------------------- casts -----
__global__ void cast_f32_to_bf16(const float* __restrict__ src,
                                 bf16_t* __restrict__ dst, int n4) {
  int i = blockIdx.x * blockDim.x + threadIdx.x;
  if (i >= n4) return;
  f32x4 v = ((const f32x4*)src)[i];
  bf16x4 o = { (bf16_t)v[0], (bf16_t)v[1], (bf16_t)v[2], (bf16_t)v[3] };
  ((bf16x4*)dst)[i] = o;
}

// ---------------- Wl[l] = W + 0.5 * B_lora @ A[l]^T  (bf16 out) -------------
// Tile 128(o) x 128(i), 4 waves (2x2), K=32 -> one MFMA per 16x16 frag.
// LDS: B_lora tile + all 5 A[l] tiles as bf16 [128][32] (48 KiB).
__global__ __launch_bounds__(256) void build_wl(
    const float* __restrict__ W, const float* __restrict__ B_lora,
    const float* __restrict__ A_lora, bf16_t* __restrict__ Wl) {
  __shared__ bf16_t Bs[128 * 32];
  __shared__ bf16_t As[5][128 * 32];
  const int tid = threadIdx.x, lane = tid & 63, wv = tid >> 6;
  const int wr = wv & 1, wc = wv >> 1;
  const int o0 = (blockIdx.x & 31) * 128, i0 = (blockIdx.x >> 5) * 128;

  // stage 6 tiles of [128][32] fp32 -> bf16 LDS; thread: 16 floats
  {
    const int row = tid >> 1, colh = (tid & 1) * 16;
    auto stage_tile = [&](const float* src, bf16_t* dst) {
      f32x4 v0 = ((const f32x4*)src)[0];
      f32x4 v1 = ((const f32x4*)src)[1];
      f32x4 v2 = ((const f32x4*)src)[2];
      f32x4 v3 = ((const f32x4*)src)[3];
      bf16x8 p0 = { (bf16_t)v0[0], (bf16_t)v0[1], (bf16_t)v0[2], (bf16_t)v0[3],
                    (bf16_t)v1[0], (bf16_t)v1[1], (bf16_t)v1[2], (bf16_t)v1[3] };
      bf16x8 p1 = { (bf16_t)v2[0], (bf16_t)v2[1], (bf16_t)v2[2], (bf16_t)v2[3],
                    (bf16_t)v3[0], (bf16_t)v3[1], (bf16_t)v3[2], (bf16_t)v3[3] };
      ((bf16x8*)dst)[0] = p0;
      ((bf16x8*)dst)[1] = p1;
    };
    stage_tile(B_lora + (size_t)(o0 + row) * R_ + colh, Bs + row * 32 + colh);
#pragma unroll
    for (int l = 0; l < 5; ++l)
      stage_tile(A_lora + ((size_t)l * DIN + i0 + row) * R_ + colh,
                 &As[l][row * 32 + colh]);
  }
  __syncthreads();

  // W tile into regs (reused across all 5 labelers)
  float w[4][4][4];
#pragma unroll
  for (int mf = 0; mf < 4; ++mf)
#pragma unroll
    for (int nf = 0; nf < 4; ++nf)
#pragma unroll
      for (int r = 0; r < 4; ++r)
        w[mf][nf][r] = W[(size_t)(o0 + wr * 64 + mf * 16 + (lane >> 4) * 4 + r) * DIN +
                         i0 + wc * 64 + nf * 16 + (lane & 15)];

  // a-frags (B_lora rows, labeler-independent)
  bf16x8 a[4];
#pragma unroll
  for (int mf = 0; mf < 4; ++mf)
    a[mf] = *(const bf16x8*)&Bs[(wr * 64 + mf * 16 + (lane & 15)) * 32 +
                                (lane >> 4) * 8];

#pragma unroll
  for (int l = 0; l < 5; ++l) {
    bf16x8 b[4];
#pragma unroll
    for (int nf = 0; nf < 4; ++nf)
      b[nf] = *(const bf16x8*)&As[l][(wc * 64 + nf * 16 + (lane & 15)) * 32 +
                                     (lane >> 4) * 8];
    f32x4 c[4][4];
#pragma unroll
    for (int mf = 0; mf < 4; ++mf)
#pragma unroll
      for (int nf = 0; nf < 4; ++nf) {
        c[mf][nf] = (f32x4){0.f, 0.f, 0.f, 0.f};
        c[mf][nf] = __builtin_amdgcn_mfma_f32_16x16x32_bf16(
            a[mf], b[nf], c[mf][nf], 0, 0, 0);
      }
    bf16_t* dst = Wl + (size_t)l * DOUT * DIN;
#pragma unroll
    for (int mf = 0; mf < 4; ++mf)
#pragma unroll
      for (int nf = 0; nf < 4; ++nf) {
        const int i_ = i0 + wc * 64 + nf * 16 + (lane & 15);
#pragma unroll
        for (int r = 0; r < 4; ++r) {
          const int o_ = o0 + wr * 64 + mf * 16 + (lane >> 4) * 4 + r;
          dst[(size_t)o_ * DIN + i_] = (bf16_t)(w[mf][nf][r] + 0.5f * c[mf][nf][r]);
        }
      }
  }
}

// ------------------------------------- out = Xb @ Wl[lab]^T + bias ----------
// 256x256 tile, BK=64, 512 threads = 8 waves (2M x 4N), each wave 128x64.
// LDS [buf][op][khalf][256 rows * 32 cols] = 128 KiB, k-half double buffer.
// 8 phases / iteration, 2 K-tiles / iteration; vmcnt(4) only at phases 4/8.
__global__ __launch_bounds__(512, 2) void main_gemm_wl(
    const bf16_t* __restrict__ Xb, const bf16_t* __restrict__ Wl,
    const int* __restrict__ lab_idx,
    const float* __restrict__ bias, float* __restrict__ out) {
  __shared__ bf16_t lds[2][2][2][8192];  // [buf][A/B][kh][256*32] = 128 KiB
  char* ldsb = (char*)&lds[0][0][0][0];

  const int tid = threadIdx.x, lane = tid & 63, wv = tid >> 6;
  const int wm = wv & 1, wn = wv >> 1;

  // XCD-aware swizzle: 1024 blocks, 8 XCDs, 128 contiguous per XCD.
  // XCD x covers m-tiles x*8..x*8+7 = exactly batch x -> one labeler per XCD.
  const int swz = (blockIdx.x & 7) * 128 + (blockIdx.x >> 3);
  const int m0 = (swz >> 4) * 256, n0 = (swz & 15) * 256;
  const int lab = lab_idx[m0 >> 11];
  const bf16_t* Wb = Wl + (size_t)lab * DOUT * DIN;

  // ---- read side: frag (row = base+(lane&15), k = ks*32+(lane>>4)*8) ------
  const int rd_off = (lane & 15) * 64 + ((((lane >> 4) ^ (lane >> 1)) & 3) << 4);
  const char* ldsA0 = ldsb + wm * 8192 + rd_off;           // buf0 A
  const char* ldsA1 = ldsA0 + 65536;                       // buf1 A
  const char* ldsB0 = ldsb + 32768 + wn * 4096 + rd_off;   // buf0 B
  const char* ldsB1 = ldsB0 + 65536;                       // buf1 B

  // ---- stage side: wave wv writes 1KB at region + wv*1024 -----------------
  const int srow = lane >> 2;
  const int scol = (((lane & 3) ^ (lane >> 3)) & 3) * 8;
  const bf16_t* pA_w = Xb + (size_t)(m0 + wv * 16 + srow) * DIN + scol;
  const bf16_t* pB_w = Wb + (size_t)(n0 + wv * 16 + srow) * DIN + scol;
  char* lAw = ldsb + wv * 1024;
  char* lBw = ldsb + 32768 + wv * 1024;

  f32x4 acc[8][4];
#pragma unroll
  for (int i = 0; i < 8; ++i)
#pragma unroll
    for (int j = 0; j < 4; ++j) acc[i][j] = (f32x4){0.f, 0.f, 0.f, 0.f};

#define STAGE_A(buf, kh, st) do {                                        \
    const bf16_t* g_ = pA_w + (st) * 64 + (kh) * 32;                     \
    bf16_t* l_ = (bf16_t*)(lAw + (buf) * 65536 + (kh) * 16384);          \
    async_cp16(g_, l_);                                                  \
    async_cp16(g_ + 128 * DIN, l_ + 4096);                               \
  } while (0)

#define STAGE_B(buf, kh, st) do {                                        \
    const bf16_t* g_ = pB_w + (st) * 64 + (kh) * 32;                     \
    bf16_t* l_ = (bf16_t*)(lBw + (buf) * 65536 + (kh) * 16384);          \
    async_cp16(g_, l_);                                                  \
    async_cp16(g_ + 128 * DIN, l_ + 4096);                               \
  } while (0)

  bf16x8 bfr[4];

#define PHASE(buf, ks, mh, LOADB, STAGE_STMT, VM) do {                   \
    const char* pa_ = (buf) ? ldsA1 : ldsA0;                             \
    const char* pb_ = (buf) ? ldsB1 : ldsB0;                             \
    bf16x8 a_[4];                                                        \
    _Pragma("unroll")                                                    \
    for (int m_ = 0; m_ < 4; ++m_)                                       \
      a_[m_] = *(const bf16x8*)(pa_ + (ks) * 16384 + ((mh) * 4 + m_) * 1024); \
    if (LOADB) {                                                         \
      _Pragma("unroll")                                                  \
      for (int n_ = 0; n_ < 4; ++n_)                                     \
        bfr[n_] = *(const bf16x8*)(pb_ + (ks) * 16384 + n_ * 1024);      \
    }                                                                    \
    STAGE_STMT;                                                          \
    __builtin_amdgcn_s_barrier();                                        \
    asm volatile("s_waitcnt lgkmcnt(0)" ::: "memory");                   \
    __builtin_amdgcn_s_setprio(1);                                       \
    _Pragma("unroll")                                                    \
    for (int m_ = 0; m_ < 4; ++m_)                                       \
      _Pragma("unroll")                                                  \
      for (int n_ = 0; n_ < 4; ++n_)                                     \
        acc[(mh) * 4 + m_][n_] = __builtin_amdgcn_mfma_f32_16x16x32_bf16( \
            a_[m_], bfr[n_], acc[(mh) * 4 + m_][n_], 0, 0, 0);           \
    __builtin_amdgcn_s_setprio(0);                                       \
    VM;                                                                  \
    __builtin_amdgcn_s_barrier();                                        \
  } while (0)

  // ---- prologue: buf0 (tile 0, both k-halves) + buf1.k0 (tile 1) ----------
  STAGE_A(0, 0, 0); STAGE_B(0, 0, 0);
  STAGE_A(0, 1, 0); STAGE_B(0, 1, 0);
  STAGE_A(1, 0, 1); STAGE_B(1, 0, 1);
  asm volatile("s_waitcnt vmcnt(4)" ::: "memory");  // buf0 fully landed
  __builtin_amdgcn_s_barrier();

  for (int i = 0; i < 32; ++i) {
    const int st1 = 2 * i + 1;
    const int st2 = (2 * i + 2 < 64) ? 2 * i + 2 : 63;  // tail: dead restage
    const int st3 = (2 * i + 3 < 64) ? 2 * i + 3 : 63;
    PHASE(0, 0, 0, 1, STAGE_A(1, 1, st1), );
    PHASE(0, 0, 1, 0, STAGE_B(1, 1, st1), );
    PHASE(0, 1, 0, 1, STAGE_A(0, 0, st2), );
    PHASE(0, 1, 1, 0, STAGE_B(0, 0, st2),
          asm volatile("s_waitcnt vmcnt(4)" ::: "memory"));
    PHASE(1, 0, 0, 1, STAGE_A(0, 1, st2), );
    PHASE(1, 0, 1, 0, STAGE_B(0, 1, st2), );
    PHASE(1, 1, 0, 1, STAGE_A(1, 0, st3), );
    PHASE(1, 1, 1, 0, STAGE_B(1, 0, st3),
          asm volatile("s_waitcnt vmcnt(4)" ::: "memory"));
  }
#undef PHASE
#undef STAGE_A
#undef STAGE_B

  // drain remaining in-flight tail stages before ending the kernel
  asm volatile("s_waitcnt vmcnt(0)" ::: "memory");

  // ---- epilogue: +bias, fp32 store. C/D: col=lane&15, row=(lane>>4)*4+reg -
#pragma unroll
  for (int nf = 0; nf < 4; ++nf) {
    const int n = n0 + wn * 64 + nf * 16 + (lane & 15);
    const float bv = bias[n];
#pragma unroll
    for (int mf = 0; mf < 8; ++mf) {
      const int m = m0 + wm * 128 + mf * 16 + (lane >> 4) * 4;
#pragma unroll
      for (int r = 0; r < 4; ++r)
        out[(size_t)(m + r) * DOUT + n] = acc[mf][nf][r] + bv;
    }
  }
}

// ===================== R3 fallback path (small ws) ==========================
__global__ __launch_bounds__(256) void transpose_loraA(
    const float* __restrict__ A, bf16_t* __restrict__ At) {
  __shared__ float tile[64][33];
  const int l = blockIdx.x / (DIN / 64);
  const int k0 = (blockIdx.x % (DIN / 64)) * 64;
  const int tid = threadIdx.x;
  {
    const int r = tid & 31, kb = tid >> 5;
#pragma unroll
    for (int p = 0; p < 8; ++p) {
      int k = p * 8 + kb;
      tile[k][r] = A[(size_t)l * DIN * R_ + (size_t)(k0 + k) * R_ + r];
    }
  }
  __syncthreads();
  {
    const int k = tid & 63, rb = tid >> 6;
#pragma unroll
    for (int p = 0; p < 8; ++p) {
      int r = p * 4 + rb;
      At[(size_t)l * R_ * DIN + (size_t)r * DIN + k0 + k] = (bf16_t)tile[k][r];
    }
  }
}

__global__ __launch_bounds__(256) void ax_partial(
    const bf16_t* __restrict__ Xb, const bf16_t* __restrict__ At,
    const int* __restrict__ lab_idx, float* __restrict__ axp) {
  __shared__ bf16_t As[128 * 64];
  __shared__ bf16_t Bs[32 * 64];
  const int tid = threadIdx.x, lane = tid & 63, wv = tid >> 6;
  const int m0 = blockIdx.x * 128;
  const int kbase = blockIdx.y * (DIN / KSPLIT);
  const int lab = lab_idx[m0 / S_];
  const bf16_t* Bsrc = At + (size_t)lab * R_ * DIN;
  f32x4 acc[2][2];
#pragma unroll
  for (int i = 0; i < 2; ++i)
#pragma unroll
    for (int j = 0; j < 2; ++j) acc[i][j] = (f32x4){0.f, 0.f, 0.f, 0.f};
  for (int kt = 0; kt < (DIN / KSPLIT) / 64; ++kt) {
    const int k0 = kbase + kt * 64;
    __syncthreads();
    {
      const int kk = (lane & 7) * 8;
#pragma unroll
      for (int j = 0; j < 4; ++j) {
        int row = j * 32 + wv * 8 + (lane >> 3);
        async_cp16(Xb + (size_t)(m0 + row) * DIN + k0 + kk,
                   As + j * 2048 + wv * 512);
      }
      int row = wv * 8 + (lane >> 3);
      async_cp16(Bsrc + (size_t)row * DIN + k0 + kk, Bs + wv * 512);
    }
    __syncthreads();
#pragma unroll
    for (int ks = 0; ks < 2; ++ks) {
      bf16x8 a[2], b[2];
#pragma unroll
      for (int mt = 0; mt < 2; ++mt)
        a[mt] = *(const bf16x8*)&As[(wv * 32 + mt * 16 + (lane & 15)) * 64 +
                                    ks * 32 + (lane >> 4) * 8];
#pragma unroll
      for (int nt = 0; nt < 2; ++nt)
        b[nt] = *(const bf16x8*)&Bs[(nt * 16 + (lane & 15)) * 64 +
                                    ks * 32 + (lane >> 4) * 8];
#pragma unroll
      for (int mt = 0; mt < 2; ++mt)
#pragma unroll
        for (int nt = 0; nt < 2; ++nt)
          acc[mt][nt] = __builtin_amdgcn_mfma_f32_16x16x32_bf16(
              a[mt], b[nt], acc[mt][nt], 0, 0, 0);
    }
  }
  float* dst = axp + (size_t)blockIdx.y * M_TOT * R_;
#pragma unroll
  for (int mt = 0; mt < 2; ++mt)
#pragma unroll
    for (int nt = 0; nt < 2; ++nt)
#pragma unroll
      for (int r = 0; r < 4; ++r) {
        int m = m0 + wv * 32 + mt * 16 + (lane >> 4) * 4 + r;
        int n = nt * 16 + (lane & 15);
        dst[(size_t)m * R_ + n] = acc[mt][nt][r];
      }
}

__global__ void ax_reduce(const float* __restrict__ axp,
                          bf16_t* __restrict__ axb, int n4) {
  int i = blockIdx.x * blockDim.x + threadIdx.x;
  if (i >= n4) return;
  f32x4 s = (f32x4){0.f, 0.f, 0.f, 0.f};
#pragma unroll
  for (int ks = 0; ks < KSPLIT; ++ks)
    s += ((const f32x4*)(axp + (size_t)ks * M_TOT * R_))[i];
  bf16x4 o = { (bf16_t)(0.5f * s[0]), (bf16_t)(0.5f * s[1]),
               (bf16_t)(0.5f * s[2]), (bf16_t)(0.5f * s[3]) };
  ((bf16x4*)axb)[i] = o;
}

__global__ __launch_bounds__(512, 2) void main_gemm(
    const bf16_t* __restrict__ Xb, const bf16_t* __restrict__ Wb,
    const bf16_t* __restrict__ axb, const bf16_t* __restrict__ Bb,
    const float* __restrict__ bias, float* __restrict__ out) {
  __shared__ bf16_t lds[2][2][2][8192];
  char* ldsb = (char*)&lds[0][0][0][0];
  const int tid = threadIdx.x, lane = tid & 63, wv = tid >> 6;
  const int wm = wv & 1, wn = wv >> 1;
  const int swz = (blockIdx.x & 7) * 128 + (blockIdx.x >> 3);
  const int m0 = (swz >> 4) * 256, n0 = (swz & 15) * 256;
  const int rd_off = (lane & 15) * 64 + ((((lane >> 4) ^ (lane >> 1)) & 3) << 4);
  const char* ldsA0 = ldsb + wm * 8192 + rd_off;
  const char* ldsA1 = ldsA0 + 65536;
  const char* ldsB0 = ldsb + 32768 + wn * 4096 + rd_off;
  const char* ldsB1 = ldsB0 + 65536;
  const int srow = lane >> 2;
  const int scol = (((lane & 3) ^ (lane >> 3)) & 3) * 8;
  const bf16_t* pA_w = Xb + (size_t)(m0 + wv * 16 + srow) * DIN + scol;
  const bf16_t* pB_w = Wb + (size_t)(n0 + wv * 16 + srow) * DIN + scol;
  char* lAw = ldsb + wv * 1024;
  char* lBw = ldsb + 32768 + wv * 1024;
  f32x4 acc[8][4];
#pragma unroll
  for (int i = 0; i < 8; ++i)
#pragma unroll
    for (int j = 0; j < 4; ++j) acc[i][j] = (f32x4){0.f, 0.f, 0.f, 0.f};
#define STAGE_A(buf, kh, st) do {                                        \
    const bf16_t* g_ = pA_w + (st) * 64 + (kh) * 32;                     \
    bf16_t* l_ = (bf16_t*)(lAw + (buf) * 65536 + (kh) * 16384);          \
    async_cp16(g_, l_);                                                  \
    async_cp16(g_ + 128 * DIN, l_ + 4096);                               \
  } while (0)
#define STAGE_B(buf, kh, st) do {                                        \
    const bf16_t* g_ = pB_w + (st) * 64 + (kh) * 32;                     \
    bf16_t* l_ = (bf16_t*)(lBw + (buf) * 65536 + (kh) * 16384);          \
    async_cp16(g_, l_);                                                  \
    async_cp16(g_ + 128 * DIN, l_ + 4096);                               \
  } while (0)
  bf16x8 bfr[4];
#define PHASE(buf, ks, mh, LOADB, STAGE_STMT, VM) do {                   \
    const char* pa_ = (buf) ? ldsA1 : ldsA0;                             \
    const char* pb_ = (buf) ? ldsB1 : ldsB0;                             \
    bf16x8 a_[4];                                                        \
    _Pragma("unroll")                                                    \
    for (int m_ = 0; m_ < 4; ++m_)                                       \
      a_[m_] = *(const bf16x8*)(pa_ + (ks) * 16384 + ((mh) * 4 + m_) * 1024); \
    if (LOADB) {                                                         \
      _Pragma("unroll")                                                  \
      for (int n_ = 0; n_ < 4; ++n_)                                     \
        bfr[n_] = *(const bf16x8*)(pb_ + (ks) * 16384 + n_ * 1024);      \
    }                                                                    \
    STAGE_STMT;                                                          \
    __builtin_amdgcn_s_barrier();                                        \
    asm volatile("s_waitcnt lgkmcnt(0)" ::: "memory");                   \
    __builtin_amdgcn_s_setprio(1);                                       \
    _Pragma("unroll")                                                    \
    for (int m_ = 0; m_ < 4; ++m_)                                       \
      _Pragma("unroll")                                                  \
      for (int n_ = 0; n_ < 4; ++n_)                                     \
        acc[(mh) * 4 + m_][n_] = __builtin_amdgcn_mfma_f32_16x16x32_bf16( \
            a_[m_], bfr[n_], acc[(mh) * 4 + m_][n_], 0, 0, 0);           \
    __builtin_amdgcn_s_setprio(0);                                       \
    VM;                                                                  \
    __builtin_amdgcn_s_barrier();                                        \
  } while (0)
  STAGE_A(0, 0, 0); STAGE_B(0, 0, 0);
  STAGE_A(0, 1, 0); STAGE_B(0, 1, 0);
  STAGE_A(1, 0, 1); STAGE_B(1, 0, 1);
  asm volatile("s_waitcnt vmcnt(4)" ::: "memory");
  __builtin_amdgcn_s_barrier();
  for (int i = 0; i < 32; ++i) {
    const int st1 = 2 * i + 1;
    const int st2 = (2 * i + 2 < 64) ? 2 * i + 2 : 63;
    const int st3 = (2 * i + 3 < 64) ? 2 * i + 3 : 63;
    PHASE(0, 0, 0, 1, STAGE_A(1, 1, st1), );
    PHASE(0, 0, 1, 0, STAGE_B(1, 1, st1), );
    PHASE(0, 1, 0, 1, STAGE_A(0, 0, st2), );
    PHASE(0, 1, 1, 0, STAGE_B(0, 0, st2),
          asm volatile("s_waitcnt vmcnt(4)" ::: "memory"));
    PHASE(1, 0, 0, 1, STAGE_A(0, 1, st2), );
    PHASE(1, 0, 1, 0, STAGE_B(0, 1, st2), );
    PHASE(1, 1, 0, 1, STAGE_A(1, 0, st3), );
    PHASE(1, 1, 1, 0, STAGE_B(1, 0, st3),
          asm volatile("s_waitcnt vmcnt(4)" ::: "memory"));
  }
  {
    const bf16_t* gA = axb + (size_t)(m0 + wv * 16 + srow) * R_ + scol;
    const bf16_t* gB = Bb + (size_t)(n0 + wv * 16 + srow) * R_ + scol;
    bf16_t* lA = (bf16_t*)lAw;
    bf16_t* lB = (bf16_t*)lBw;
    async_cp16(gA, lA); async_cp16(gA + 128 * R_, lA + 4096);
    async_cp16(gB, lB); async_cp16(gB + 128 * R_, lB + 4096);
    asm volatile("s_waitcnt vmcnt(0)" ::: "memory");
    __builtin_amdgcn_s_barrier();
    bf16x8 a8[8];
#pragma unroll
    for (int m = 0; m < 8; ++m)
      a8[m] = *(const bf16x8*)(ldsA0 + m * 1024);
#pragma unroll
    for (int n = 0; n < 4; ++n)
      bfr[n] = *(const bf16x8*)(ldsB0 + n * 1024);
    asm volatile("s_waitcnt lgkmcnt(0)" ::: "memory");
#pragma unroll
    for (int m = 0; m < 8; ++m)
#pragma unroll
      for (int n = 0; n < 4; ++n)
        acc[m][n] = __builtin_amdgcn_mfma_f32_16x16x32_bf16(
            a8[m], bfr[n], acc[m][n], 0, 0, 0);
  }
#undef PHASE
#undef STAGE_A
#undef STAGE_B
#pragma unroll
  for (int nf = 0; nf < 4; ++nf) {
    const int n = n0 + wn * 64 + nf * 16 + (lane & 15);
    const float bv = bias[n];
#pragma unroll
    for (int mf = 0; mf < 8; ++mf) {
      const int m = m0 + wm * 128 + mf * 16 + (lane >> 4) * 4;
#pragma unroll
      for (int r = 0; r < 4; ++r)
        out[(size_t)(m + r) * DOUT + n] = acc[mf][nf][r] + bv;
    }
  }
}

// ---------------------------------------------------------------------------
extern "C" void kernel_launch(void* const* d_in, const int* in_sizes, int n_in,
                              void* d_out, int out_size, void* d_ws, size_t ws_size,
                              hipStream_t stream) {
  const float* X      = (const float*)d_in[0];  // [8,2048,4096]
  const float* W      = (const float*)d_in[1];  // [4096,4096]
  const float* bias   = (const float*)d_in[2];  // [4096]
  const float* lora_A = (const float*)d_in[3];  // [5,4096,32]
  const float* lora_B = (const float*)d_in[4];  // [4096,32]
  const int*   lab    = (const int*)d_in[5];    // [8]
  float* out = (float*)d_out;
  char* ws = (char*)d_ws;

  if (ws_size >= 302000000UL) {
    // Folded path: ws = Xb 128M | Wl 5x32M = 160M  (288 MB total)
    bf16_t* Xb = (bf16_t*)(ws);
    bf16_t* Wl = (bf16_t*)(ws + 134217728UL);
    cast_f32_to_bf16<<<65536, 256, 0, stream>>>(X, Xb, (M_TOT * DIN) / 4);
    build_wl<<<1024, 256, 0, stream>>>(W, lora_B, lora_A, Wl);
    main_gemm_wl<<<1024, 512, 0, stream>>>(Xb, Wl, lab, bias, out);
  } else {
    // R3 fallback: Xb 128M | Wb 32M | At 1.25M | Bb 256K | axb 1M | axp 16M
    bf16_t* Xb  = (bf16_t*)(ws);
    bf16_t* Wb  = (bf16_t*)(ws + 134217728UL);
    bf16_t* At  = (bf16_t*)(ws + 167772160UL);
    bf16_t* Bb  = (bf16_t*)(ws + 169082880UL);
    bf16_t* axb = (bf16_t*)(ws + 169345024UL);
    float*  axp = (float*)(ws + 170393600UL);
    cast_f32_to_bf16<<<65536, 256, 0, stream>>>(X, Xb, (M_TOT * DIN) / 4);
    cast_f32_to_bf16<<<16384, 256, 0, stream>>>(W, Wb, (DOUT * DIN) / 4);
    cast_f32_to_bf16<<<128, 256, 0, stream>>>(lora_B, Bb, (DOUT * R_) / 4);
    transpose_loraA<<<5 * (DIN / 64), 256, 0, stream>>>(lora_A, At);
    ax_partial<<<dim3(M_TOT / 128, KSPLIT), 256, 0, stream>>>(Xb, At, lab, axp);
    ax_reduce<<<(M_TOT * R_ / 4 + 255) / 256, 256, 0, stream>>>(
        axp, axb, M_TOT * R_ / 4);
    dim3 grid(DOUT / 128, M_TOT / 128);
    main_gemm<<<grid, 512, 0, stream>>>(Xb, Wb, axb, Bb, bias, out);
  }
}